// Round 6
// baseline (434.033 us; speedup 1.0000x reference)
//
#include <hip/hip_runtime.h>
#include <hip/hip_bf16.h>

#define EPSF 1e-5f
#define IOU_THRF 0.9f
#define NBOX 9216
#define NWORDS 144   // 9216/64
#define CAND_CAP 4096
#define FIRE_CAP 1024

// ---------------- depthwise 3x3 conv, C=256, 32x32, pad 1 ----------------
__global__ __launch_bounds__(256) void dw_conv(const float* __restrict__ x,
                                               const float* __restrict__ w,
                                               float* __restrict__ h0) {
    int idx = blockIdx.x * 256 + threadIdx.x;   // 262144 threads
    int c = idx >> 10, p = idx & 1023;
    int yy = p >> 5, xx = p & 31;
    const float* xi = x + (c << 10);
    const float* wc = w + c * 9;
    float acc = 0.f;
    #pragma unroll
    for (int dy = -1; dy <= 1; ++dy) {
        int y2 = yy + dy;
        if ((unsigned)y2 >= 32u) continue;
        #pragma unroll
        for (int dx = -1; dx <= 1; ++dx) {
            int x2 = xx + dx;
            if ((unsigned)x2 >= 32u) continue;
            acc += wc[(dy + 1) * 3 + (dx + 1)] * xi[y2 * 32 + x2];
        }
    }
    h0[idx] = acc;
}

// ---------------- pointwise 256x256 GEMM + BN1 + leaky relu ----------------
__global__ __launch_bounds__(256) void pw_conv(const float* __restrict__ h0,
                                               const float* __restrict__ w,
                                               const float* __restrict__ g,
                                               const float* __restrict__ b,
                                               const float* __restrict__ mu,
                                               const float* __restrict__ var,
                                               float* __restrict__ h1) {
    int p = blockIdx.x * 256 + threadIdx.x;
    int o0 = blockIdx.y * 4;
    float acc0 = 0.f, acc1 = 0.f, acc2 = 0.f, acc3 = 0.f;
    for (int c = 0; c < 256; ++c) {
        float hv = h0[(c << 10) + p];
        acc0 += w[(o0 + 0) * 256 + c] * hv;
        acc1 += w[(o0 + 1) * 256 + c] * hv;
        acc2 += w[(o0 + 2) * 256 + c] * hv;
        acc3 += w[(o0 + 3) * 256 + c] * hv;
    }
    float accs[4] = {acc0, acc1, acc2, acc3};
    #pragma unroll
    for (int k = 0; k < 4; ++k) {
        int o = o0 + k;
        float inv = 1.0f / sqrtf(var[o] + EPSF);
        float v = (accs[k] - mu[o]) * (inv * g[o]) + b[o];
        v = (v >= 0.f) ? v : 0.01f * v;
        h1[(o << 10) + p] = v;
    }
}

// ---------------- heads: anc (36 ch) + obj (9 ch) GEMV + BN + decode ----------------
__global__ __launch_bounds__(256) void heads(const float* __restrict__ h1,
                                             const float* __restrict__ anc_w,
                                             const float* __restrict__ ag,
                                             const float* __restrict__ ab,
                                             const float* __restrict__ am,
                                             const float* __restrict__ av,
                                             const float* __restrict__ obj_w,
                                             const float* __restrict__ og,
                                             const float* __restrict__ ob,
                                             const float* __restrict__ om,
                                             const float* __restrict__ ov,
                                             const float* __restrict__ anchors,
                                             float* __restrict__ boxes,
                                             float* __restrict__ scores) {
    int p = blockIdx.x * 256 + threadIdx.x;
    int o = blockIdx.y;
    const float* wrow = (o < 36) ? (anc_w + o * 256) : (obj_w + (o - 36) * 256);
    float acc = 0.f;
    for (int c = 0; c < 256; ++c) acc += wrow[c] * h1[(c << 10) + p];
    if (o < 36) {
        float inv = 1.0f / sqrtf(av[o] + EPSF);
        float v = (acc - am[o]) * (inv * ag[o]) + ab[o];
        v = fminf(fmaxf(v, 0.f), 6.f);           // clip 0..6
        int a = o >> 2, k = o & 3;
        float anch = anchors[a * 4 + k];
        float val = (k < 2) ? (v + anch) : (expf(v) * anch);
        boxes[(size_t)(a * 1024 + p) * 4 + k] = val;
    } else {
        int a = o - 36;
        float inv = 1.0f / sqrtf(ov[a] + EPSF);
        float v = (acc - om[a]) * (inv * og[a]) + ob[a];
        scores[a * 1024 + p] = 1.0f / (1.0f + expf(-v));
    }
}

// ---------------- rank = stable-descending-argsort position, O(N^2) count ----------------
__global__ __launch_bounds__(256) void rank_partial(const float* __restrict__ scores,
                                                    unsigned* __restrict__ rank) {
    __shared__ float4 sm[288];
    int mbase = blockIdx.y * 1152;
    for (int t = threadIdx.x; t < 288; t += 256)
        sm[t] = ((const float4*)(scores + mbase))[t];
    __syncthreads();
    int n = blockIdx.x * 256 + threadIdx.x;
    float s = scores[n];
    unsigned cnt = 0;
    for (int q = 0; q < 288; ++q) {
        float4 v = sm[q];
        int m = mbase + q * 4;
        cnt += (v.x > s) || (v.x == s && (m + 0) < n);
        cnt += (v.y > s) || (v.y == s && (m + 1) < n);
        cnt += (v.z > s) || (v.z == s && (m + 2) < n);
        cnt += (v.w > s) || (v.w == s && (m + 3) < n);
    }
    atomicAdd(&rank[n], cnt);
}

// ---------------- scatter into sorted order ----------------
__global__ __launch_bounds__(256) void scatter_sorted(const float* __restrict__ boxes,
                                                      const unsigned* __restrict__ rank,
                                                      int* __restrict__ order,
                                                      float* __restrict__ sboxes,
                                                      float* __restrict__ sareas) {
    int n = blockIdx.x * 256 + threadIdx.x;
    unsigned r = rank[n];
    order[r] = n;
    float4 bx = ((const float4*)boxes)[n];
    ((float4*)sboxes)[r] = bx;
    sareas[r] = (bx.z - bx.x) * (bx.w - bx.y);
}

// ---------------- candidate detection: rnz64 bit i = exists j>i with IOU>thr ----------------
// grid (18 stripes of 512 cols, 36 row-blocks of 256 rows). No mask stores.
__global__ __launch_bounds__(256) void cand_detect(const float* __restrict__ sboxes,
                                                   const float* __restrict__ sareas,
                                                   unsigned long long* __restrict__ rnz64) {
    __shared__ float4 CB[512];
    __shared__ float CAR[512];
    int s = blockIdx.x, rb = blockIdx.y;
    if (s * 512 + 511 <= rb * 256) return;   // whole tile has j <= i
    int tid = threadIdx.x;
    int i = rb * 256 + tid;
    #pragma unroll
    for (int k = 0; k < 2; ++k) {
        int idx = tid + k * 256;
        int j = s * 512 + idx;
        CB[idx] = ((const float4*)sboxes)[j];
        CAR[idx] = sareas[j];
    }
    __syncthreads();
    float4 b = ((const float4*)sboxes)[i];
    float ar = sareas[i];
    bool any = false;
    for (int idx = 0; idx < 512; ++idx) {
        int j = s * 512 + idx;
        float4 cb = CB[idx];
        float ix = fminf(b.z, cb.z) - fmaxf(b.x, cb.x);
        float iy = fminf(b.w, cb.w) - fmaxf(b.y, cb.y);
        float inter = fmaxf(ix, 0.f) * fmaxf(iy, 0.f);
        float denom = ar + CAR[idx] - inter;
        // conservative multiply prescreen; exact division (reference-identical) on near-hits
        if (j > i && inter > 0.85f * denom) {
            if (inter / denom > IOU_THRF) any = true;
        }
    }
    unsigned long long bal = __ballot(any);
    if ((tid & 63) == 0) atomicOr(&rnz64[rb * 4 + (tid >> 6)], bal);
}

// ---------------- compact candidates (order-preserving), 1 wave ----------------
__global__ __launch_bounds__(64) void compact_cand(const unsigned long long* __restrict__ rnz64,
                                                   const float* __restrict__ sboxes,
                                                   const float* __restrict__ sareas,
                                                   int* __restrict__ cidx,
                                                   float4* __restrict__ cboxes,
                                                   float* __restrict__ carea,
                                                   int* __restrict__ knum) {
    int lane = threadIdx.x;
    int base = 0;
    for (int w = 0; w < NWORDS; ++w) {
        unsigned long long bits = rnz64[w];
        if (bits & (1ull << lane)) {
            int pos = base + (int)__popcll(bits & ((1ull << lane) - 1ull));
            if (pos < CAND_CAP) {
                int i = w * 64 + lane;
                cidx[pos] = i;
                cboxes[pos] = ((const float4*)sboxes)[i];
                carea[pos] = sareas[i];
            }
        }
        base += (int)__popcll(bits);
    }
    if (lane == 0) knum[0] = base < CAND_CAP ? base : CAND_CAP;
}

// ---------------- candidate x candidate gating matrix ----------------
// gate[a*64 + w] bit t = candidate a suppresses candidate w*64+t (ordinal >, IOU>thr)
__global__ __launch_bounds__(256) void gate_build(const float4* __restrict__ cboxes,
                                                  const float* __restrict__ carea,
                                                  const int* __restrict__ knum,
                                                  unsigned long long* __restrict__ gate) {
    int Kc = knum[0];
    int a = blockIdx.x * 4 + (threadIdx.x >> 6);
    int w = threadIdx.x & 63;
    if (a >= Kc) return;
    float4 b = cboxes[a];
    float ar = carea[a];
    unsigned long long bits = 0ull;
    int cbase = w * 64;
    if (cbase < Kc) {
        int lim = Kc - cbase; if (lim > 64) lim = 64;
        for (int t = 0; t < lim; ++t) {
            int c = cbase + t;
            if (c > a) {
                float4 cb = cboxes[c];
                float ix = fminf(b.z, cb.z) - fmaxf(b.x, cb.x);
                float iy = fminf(b.w, cb.w) - fmaxf(b.y, cb.y);
                float inter = fmaxf(ix, 0.f) * fmaxf(iy, 0.f);
                float denom = ar + carea[c] - inter;
                if (inter > 0.85f * denom) {
                    if (inter / denom > IOU_THRF) bits |= (1ull << t);
                }
            }
        }
    }
    gate[(size_t)a * 64 + w] = bits;
}

// ---------------- serial greedy scan over candidate ordinals ----------------
__device__ inline unsigned long long rdl64(unsigned long long v, int l) {
    unsigned lo = (unsigned)__builtin_amdgcn_readlane((int)(unsigned)(v & 0xffffffffull), l);
    unsigned hi = (unsigned)__builtin_amdgcn_readlane((int)(unsigned)(v >> 32), l);
    return ((unsigned long long)hi << 32) | lo;
}

__global__ __launch_bounds__(64) void nms_scan2(const unsigned long long* __restrict__ gate,
                                                const int* __restrict__ knum,
                                                int* __restrict__ fire_ord,
                                                int* __restrict__ fire_cnt) {
    int lane = threadIdx.x;
    int Kc = knum[0];
    int nw = (Kc + 63) >> 6;
    unsigned long long sup = 0ull;   // lane l owns suppressed bits for ordinals l*64..l*64+63
    int nf = 0;
    for (int w = 0; w < nw; ++w) {
        int rem = Kc - w * 64;
        unsigned long long mskw = (rem >= 64) ? ~0ull : ((1ull << rem) - 1ull);
        unsigned long long alive = ~rdl64(sup, w) & mskw;
        while (alive) {
            int t = __builtin_ctzll(alive);
            int o = w * 64 + t;
            if (lane == 0 && nf < FIRE_CAP) fire_ord[nf] = o;
            ++nf;
            unsigned long long g = gate[(size_t)o * 64 + lane];   // 512B coalesced
            sup |= g;
            alive &= ~(1ull << t);
            alive &= ~rdl64(g, w);
        }
    }
    if (lane == 0) fire_cnt[0] = nf < FIRE_CAP ? nf : FIRE_CAP;
}

// ---------------- finalize: recompute suppression vs fires, write output ----------------
__global__ __launch_bounds__(256) void finalize(const float* __restrict__ sboxes,
                                                const float* __restrict__ sareas,
                                                const float* __restrict__ scores,
                                                const int* __restrict__ order,
                                                const float4* __restrict__ cboxes,
                                                const float* __restrict__ carea,
                                                const int* __restrict__ cidx,
                                                const int* __restrict__ fire_ord,
                                                const int* __restrict__ fire_cnt,
                                                float* __restrict__ out) {
    __shared__ float4 FB[FIRE_CAP];
    __shared__ float FA[FIRE_CAP];
    __shared__ int FP[FIRE_CAP];
    int tid = threadIdx.x;
    int fc = fire_cnt[0];
    for (int k = tid; k < fc; k += 256) {
        int o = fire_ord[k];
        FB[k] = cboxes[o];
        FA[k] = carea[o];
        FP[k] = cidx[o];   // sorted position of the fire
    }
    __syncthreads();
    int j = blockIdx.x * 256 + tid;   // sorted index
    float4 b = ((const float4*)sboxes)[j];
    float aj = sareas[j];
    bool supp = false;
    for (int k = 0; k < fc; ++k) {
        float4 f = FB[k];
        float ix = fminf(b.z, f.z) - fmaxf(b.x, f.x);
        float iy = fminf(b.w, f.w) - fmaxf(b.y, f.y);
        float inter = fmaxf(ix, 0.f) * fmaxf(iy, 0.f);
        float denom = FA[k] + aj - inter;
        if (FP[k] < j && inter > 0.85f * denom) {
            if (inter / denom > IOU_THRF) supp = true;
        }
    }
    int n = order[j];
    float m = supp ? 0.f : 1.f;
    out[(size_t)n * 5 + 0] = b.x * m;
    out[(size_t)n * 5 + 1] = b.y * m;
    out[(size_t)n * 5 + 2] = b.z * m;
    out[(size_t)n * 5 + 3] = b.w * m;
    out[(size_t)n * 5 + 4] = scores[n] * m;
}

extern "C" void kernel_launch(void* const* d_in, const int* in_sizes, int n_in,
                              void* d_out, int out_size, void* d_ws, size_t ws_size,
                              hipStream_t stream) {
    const float* x      = (const float*)d_in[0];
    const float* anchors= (const float*)d_in[1];
    const float* dw_w   = (const float*)d_in[2];
    const float* pw_w   = (const float*)d_in[3];
    const float* bn1g   = (const float*)d_in[4];
    const float* bn1b   = (const float*)d_in[5];
    const float* bn1m   = (const float*)d_in[6];
    const float* bn1v   = (const float*)d_in[7];
    const float* anc_w  = (const float*)d_in[8];
    const float* ag     = (const float*)d_in[9];
    const float* ab     = (const float*)d_in[10];
    const float* am     = (const float*)d_in[11];
    const float* av     = (const float*)d_in[12];
    const float* obj_w  = (const float*)d_in[13];
    const float* og     = (const float*)d_in[14];
    const float* ob     = (const float*)d_in[15];
    const float* om     = (const float*)d_in[16];
    const float* ov     = (const float*)d_in[17];
    float* out = (float*)d_out;

    char* ws = (char*)d_ws;
    size_t off = 0;
    auto alloc = [&](size_t bytes) -> char* {
        char* p = ws + off;
        off = (off + bytes + 255) & ~(size_t)255;
        return p;
    };
    float* h0      = (float*)alloc(256 * 1024 * 4);
    float* h1      = (float*)alloc(256 * 1024 * 4);
    float* boxes   = (float*)alloc(NBOX * 4 * 4);
    float* scores  = (float*)alloc(NBOX * 4);
    unsigned* rank = (unsigned*)alloc(NBOX * 4);
    int* order     = (int*)alloc(NBOX * 4);
    float* sboxes  = (float*)alloc(NBOX * 4 * 4);
    float* sareas  = (float*)alloc(NBOX * 4);
    unsigned long long* rnz64 = (unsigned long long*)alloc(NWORDS * 8);
    int* cidx      = (int*)alloc(CAND_CAP * 4);
    float4* cboxes = (float4*)alloc(CAND_CAP * 16);
    float* carea   = (float*)alloc(CAND_CAP * 4);
    int* knum      = (int*)alloc(256);
    int* fire_ord  = (int*)alloc(FIRE_CAP * 4);
    int* fire_cnt  = (int*)alloc(256);
    unsigned long long* gate = (unsigned long long*)alloc((size_t)CAND_CAP * 64 * 8);

    hipMemsetAsync(rank, 0, NBOX * 4, stream);
    hipMemsetAsync(rnz64, 0, NWORDS * 8, stream);

    dw_conv<<<1024, 256, 0, stream>>>(x, dw_w, h0);
    pw_conv<<<dim3(4, 64), 256, 0, stream>>>(h0, pw_w, bn1g, bn1b, bn1m, bn1v, h1);
    heads<<<dim3(4, 45), 256, 0, stream>>>(h1, anc_w, ag, ab, am, av,
                                           obj_w, og, ob, om, ov, anchors, boxes, scores);
    rank_partial<<<dim3(36, 8), 256, 0, stream>>>(scores, rank);
    scatter_sorted<<<36, 256, 0, stream>>>(boxes, rank, order, sboxes, sareas);
    cand_detect<<<dim3(18, 36), 256, 0, stream>>>(sboxes, sareas, rnz64);
    compact_cand<<<1, 64, 0, stream>>>(rnz64, sboxes, sareas, cidx, cboxes, carea, knum);
    gate_build<<<CAND_CAP / 4, 256, 0, stream>>>(cboxes, carea, knum, gate);
    nms_scan2<<<1, 64, 0, stream>>>(gate, knum, fire_ord, fire_cnt);
    finalize<<<36, 256, 0, stream>>>(sboxes, sareas, scores, order,
                                     cboxes, carea, cidx, fire_ord, fire_cnt, out);
}

// Round 7
// 366.472 us; speedup vs baseline: 1.1844x; 1.1844x over previous
//
#include <hip/hip_runtime.h>
#include <hip/hip_bf16.h>

#define EPSF 1e-5f
#define IOU_THRF 0.9f
#define NBOX 9216
#define NWORDS 144   // 9216/64
#define CAND_CAP 4096
#define FIRE_CAP 1024
#define NTILES 666   // 36*37/2 upper-tri 256x256 tiles

// ---------------- depthwise 3x3 conv, C=256, 32x32, pad 1 ----------------
__global__ __launch_bounds__(256) void dw_conv(const float* __restrict__ x,
                                               const float* __restrict__ w,
                                               float* __restrict__ h0) {
    int idx = blockIdx.x * 256 + threadIdx.x;   // 262144 threads
    int c = idx >> 10, p = idx & 1023;
    int yy = p >> 5, xx = p & 31;
    const float* xi = x + (c << 10);
    const float* wc = w + c * 9;
    float acc = 0.f;
    #pragma unroll
    for (int dy = -1; dy <= 1; ++dy) {
        int y2 = yy + dy;
        if ((unsigned)y2 >= 32u) continue;
        #pragma unroll
        for (int dx = -1; dx <= 1; ++dx) {
            int x2 = xx + dx;
            if ((unsigned)x2 >= 32u) continue;
            acc += wc[(dy + 1) * 3 + (dx + 1)] * xi[y2 * 32 + x2];
        }
    }
    h0[idx] = acc;
}

// ---------------- pointwise 256x256 GEMM + BN1 + leaky relu ----------------
__global__ __launch_bounds__(256) void pw_conv(const float* __restrict__ h0,
                                               const float* __restrict__ w,
                                               const float* __restrict__ g,
                                               const float* __restrict__ b,
                                               const float* __restrict__ mu,
                                               const float* __restrict__ var,
                                               float* __restrict__ h1) {
    int p = blockIdx.x * 256 + threadIdx.x;
    int o0 = blockIdx.y * 4;
    float acc0 = 0.f, acc1 = 0.f, acc2 = 0.f, acc3 = 0.f;
    for (int c = 0; c < 256; ++c) {
        float hv = h0[(c << 10) + p];
        acc0 += w[(o0 + 0) * 256 + c] * hv;
        acc1 += w[(o0 + 1) * 256 + c] * hv;
        acc2 += w[(o0 + 2) * 256 + c] * hv;
        acc3 += w[(o0 + 3) * 256 + c] * hv;
    }
    float accs[4] = {acc0, acc1, acc2, acc3};
    #pragma unroll
    for (int k = 0; k < 4; ++k) {
        int o = o0 + k;
        float inv = 1.0f / sqrtf(var[o] + EPSF);
        float v = (accs[k] - mu[o]) * (inv * g[o]) + b[o];
        v = (v >= 0.f) ? v : 0.01f * v;
        h1[(o << 10) + p] = v;
    }
}

// ---------------- heads: anc (36 ch) + obj (9 ch) GEMV + BN + decode ----------------
__global__ __launch_bounds__(256) void heads(const float* __restrict__ h1,
                                             const float* __restrict__ anc_w,
                                             const float* __restrict__ ag,
                                             const float* __restrict__ ab,
                                             const float* __restrict__ am,
                                             const float* __restrict__ av,
                                             const float* __restrict__ obj_w,
                                             const float* __restrict__ og,
                                             const float* __restrict__ ob,
                                             const float* __restrict__ om,
                                             const float* __restrict__ ov,
                                             const float* __restrict__ anchors,
                                             float* __restrict__ boxes,
                                             float* __restrict__ scores) {
    int p = blockIdx.x * 256 + threadIdx.x;
    int o = blockIdx.y;
    const float* wrow = (o < 36) ? (anc_w + o * 256) : (obj_w + (o - 36) * 256);
    float acc = 0.f;
    for (int c = 0; c < 256; ++c) acc += wrow[c] * h1[(c << 10) + p];
    if (o < 36) {
        float inv = 1.0f / sqrtf(av[o] + EPSF);
        float v = (acc - am[o]) * (inv * ag[o]) + ab[o];
        v = fminf(fmaxf(v, 0.f), 6.f);           // clip 0..6
        int a = o >> 2, k = o & 3;
        float anch = anchors[a * 4 + k];
        float val = (k < 2) ? (v + anch) : (expf(v) * anch);
        boxes[(size_t)(a * 1024 + p) * 4 + k] = val;
    } else {
        int a = o - 36;
        float inv = 1.0f / sqrtf(ov[a] + EPSF);
        float v = (acc - om[a]) * (inv * og[a]) + ob[a];
        scores[a * 1024 + p] = 1.0f / (1.0f + expf(-v));
    }
}

// ---------------- rank = stable-descending-argsort position, O(N^2) count ----------------
__global__ __launch_bounds__(256) void rank_partial(const float* __restrict__ scores,
                                                    unsigned* __restrict__ rank) {
    __shared__ float4 sm[288];
    int mbase = blockIdx.y * 1152;
    for (int t = threadIdx.x; t < 288; t += 256)
        sm[t] = ((const float4*)(scores + mbase))[t];
    __syncthreads();
    int n = blockIdx.x * 256 + threadIdx.x;
    float s = scores[n];
    unsigned cnt = 0;
    for (int q = 0; q < 288; ++q) {
        float4 v = sm[q];
        int m = mbase + q * 4;
        cnt += (v.x > s) || (v.x == s && (m + 0) < n);
        cnt += (v.y > s) || (v.y == s && (m + 1) < n);
        cnt += (v.z > s) || (v.z == s && (m + 2) < n);
        cnt += (v.w > s) || (v.w == s && (m + 3) < n);
    }
    atomicAdd(&rank[n], cnt);
}

// ---------------- scatter into sorted order ----------------
__global__ __launch_bounds__(256) void scatter_sorted(const float* __restrict__ boxes,
                                                      const unsigned* __restrict__ rank,
                                                      int* __restrict__ order,
                                                      float* __restrict__ sboxes,
                                                      float* __restrict__ sareas) {
    int n = blockIdx.x * 256 + threadIdx.x;
    unsigned r = rank[n];
    order[r] = n;
    float4 bx = ((const float4*)boxes)[n];
    ((float4*)sboxes)[r] = bx;
    sareas[r] = (bx.z - bx.x) * (bx.w - bx.y);
}

// ---------------- candidate detection over upper-tri 256x256 tiles ----------------
// grid = 666 tiles (rb<=s), 256 thr; thread=row, SoA float4 LDS col reads.
__global__ __launch_bounds__(256) void cand_detect(const float* __restrict__ sboxes,
                                                   const float* __restrict__ sareas,
                                                   unsigned long long* __restrict__ rnz64) {
    __shared__ float CX1[256], CY1[256], CX2[256], CY2[256], CAR[256];
    // triangular decode: tile t -> (rb, s), s >= rb
    int rem = blockIdx.x, rb = 0;
    while (rem >= 36 - rb) { rem -= 36 - rb; ++rb; }
    int s = rb + rem;
    int tid = threadIdx.x;
    int i = rb * 256 + tid;
    {
        int j = s * 256 + tid;
        float4 cb = ((const float4*)sboxes)[j];
        CX1[tid] = cb.x; CY1[tid] = cb.y; CX2[tid] = cb.z; CY2[tid] = cb.w;
        CAR[tid] = sareas[j];
    }
    __syncthreads();
    float4 b = ((const float4*)sboxes)[i];
    float ar = sareas[i];
    bool any = false;

    if (s == rb) {
        // diagonal tile: ragged loop, j > i
        for (int idx = tid + 1; idx < 256; ++idx) {
            float ix = fminf(b.z, CX2[idx]) - fmaxf(b.x, CX1[idx]);
            float iy = fminf(b.w, CY2[idx]) - fmaxf(b.y, CY1[idx]);
            float inter = fmaxf(ix, 0.f) * fmaxf(iy, 0.f);
            float denom = ar + CAR[idx] - inter;
            if (inter > 0.85f * denom) {
                if (inter / denom > IOU_THRF) any = true;
            }
        }
    } else {
        const float4* X1v = (const float4*)CX1;
        const float4* Y1v = (const float4*)CY1;
        const float4* X2v = (const float4*)CX2;
        const float4* Y2v = (const float4*)CY2;
        const float4* ARv = (const float4*)CAR;
        #pragma unroll 2
        for (int q = 0; q < 64; ++q) {
            float4 x1 = X1v[q], y1 = Y1v[q], x2 = X2v[q], y2 = Y2v[q], aa = ARv[q];
            #define CCHK(k) { \
                float ix = fminf(b.z, x2.k) - fmaxf(b.x, x1.k); \
                float iy = fminf(b.w, y2.k) - fmaxf(b.y, y1.k); \
                float inter = fmaxf(ix, 0.f) * fmaxf(iy, 0.f);  \
                float denom = ar + aa.k - inter;                \
                if (inter > 0.85f * denom) {                    \
                    if (inter / denom > IOU_THRF) any = true;   \
                } }
            CCHK(x) CCHK(y) CCHK(z) CCHK(w)
            #undef CCHK
        }
    }
    unsigned long long bal = __ballot(any);
    if ((tid & 63) == 0) atomicOr(&rnz64[rb * 4 + (tid >> 6)], bal);
}

// ---------------- compact candidates (order-preserving), 1 wave ----------------
__global__ __launch_bounds__(64) void compact_cand(const unsigned long long* __restrict__ rnz64,
                                                   const float* __restrict__ sboxes,
                                                   const float* __restrict__ sareas,
                                                   int* __restrict__ cidx,
                                                   float4* __restrict__ cboxes,
                                                   float* __restrict__ carea,
                                                   int* __restrict__ knum) {
    int lane = threadIdx.x;
    int base = 0;
    for (int w = 0; w < NWORDS; ++w) {
        unsigned long long bits = rnz64[w];
        if (bits & (1ull << lane)) {
            int pos = base + (int)__popcll(bits & ((1ull << lane) - 1ull));
            if (pos < CAND_CAP) {
                int i = w * 64 + lane;
                cidx[pos] = i;
                cboxes[pos] = ((const float4*)sboxes)[i];
                carea[pos] = sareas[i];
            }
        }
        base += (int)__popcll(bits);
    }
    if (lane == 0) knum[0] = base < CAND_CAP ? base : CAND_CAP;
}

// ---------------- candidate x candidate gating matrix ----------------
__global__ __launch_bounds__(256) void gate_build(const float4* __restrict__ cboxes,
                                                  const float* __restrict__ carea,
                                                  const int* __restrict__ knum,
                                                  unsigned long long* __restrict__ gate) {
    int Kc = knum[0];
    int a = blockIdx.x * 4 + (threadIdx.x >> 6);
    int w = threadIdx.x & 63;
    if (a >= Kc) return;
    float4 b = cboxes[a];
    float ar = carea[a];
    unsigned long long bits = 0ull;
    int cbase = w * 64;
    if (cbase < Kc) {
        int lim = Kc - cbase; if (lim > 64) lim = 64;
        for (int t = 0; t < lim; ++t) {
            int c = cbase + t;
            if (c > a) {
                float4 cb = cboxes[c];
                float ix = fminf(b.z, cb.z) - fmaxf(b.x, cb.x);
                float iy = fminf(b.w, cb.w) - fmaxf(b.y, cb.y);
                float inter = fmaxf(ix, 0.f) * fmaxf(iy, 0.f);
                float denom = ar + carea[c] - inter;
                if (inter > 0.85f * denom) {
                    if (inter / denom > IOU_THRF) bits |= (1ull << t);
                }
            }
        }
    }
    gate[(size_t)a * 64 + w] = bits;
}

// ---------------- serial greedy scan, batched speculative fires ----------------
__device__ inline unsigned long long rdl64(unsigned long long v, int l) {
    unsigned lo = (unsigned)__builtin_amdgcn_readlane((int)(unsigned)(v & 0xffffffffull), l);
    unsigned hi = (unsigned)__builtin_amdgcn_readlane((int)(unsigned)(v >> 32), l);
    return ((unsigned long long)hi << 32) | lo;
}

__global__ __launch_bounds__(64) void nms_scan2(const unsigned long long* __restrict__ gate,
                                                const int* __restrict__ knum,
                                                int* __restrict__ fire_ord,
                                                int* __restrict__ fire_cnt) {
    int lane = threadIdx.x;
    int Kc = knum[0];
    int nw = (Kc + 63) >> 6;
    unsigned long long sup = 0ull;   // lane l owns suppressed bits for ordinals l*64..
    int nf = 0;
    for (int w = 0; w < nw; ++w) {
        int rem = Kc - w * 64;
        unsigned long long mskw = (rem >= 64) ? ~0ull : ((1ull << rem) - 1ull);
        unsigned long long alive = ~rdl64(sup, w) & mskw;
        while (alive) {
            // snapshot up to 8 alive ordinals, issue all loads, then settle
            unsigned long long snap = alive;
            int t0 = __builtin_ctzll(snap); snap &= snap - 1;
            int t1 = -1, t2 = -1, t3 = -1, t4 = -1, t5 = -1, t6 = -1, t7 = -1;
            if (snap) { t1 = __builtin_ctzll(snap); snap &= snap - 1; }
            if (snap) { t2 = __builtin_ctzll(snap); snap &= snap - 1; }
            if (snap) { t3 = __builtin_ctzll(snap); snap &= snap - 1; }
            if (snap) { t4 = __builtin_ctzll(snap); snap &= snap - 1; }
            if (snap) { t5 = __builtin_ctzll(snap); snap &= snap - 1; }
            if (snap) { t6 = __builtin_ctzll(snap); snap &= snap - 1; }
            if (snap) { t7 = __builtin_ctzll(snap); snap &= snap - 1; }
            int u1 = t1 < 0 ? t0 : t1, u2 = t2 < 0 ? t0 : t2, u3 = t3 < 0 ? t0 : t3;
            int u4 = t4 < 0 ? t0 : t4, u5 = t5 < 0 ? t0 : t5, u6 = t6 < 0 ? t0 : t6;
            int u7 = t7 < 0 ? t0 : t7;
            size_t wb = (size_t)(w << 6);
            unsigned long long g0 = gate[(wb + t0) * 64 + lane];
            unsigned long long g1 = gate[(wb + u1) * 64 + lane];
            unsigned long long g2 = gate[(wb + u2) * 64 + lane];
            unsigned long long g3 = gate[(wb + u3) * 64 + lane];
            unsigned long long g4 = gate[(wb + u4) * 64 + lane];
            unsigned long long g5 = gate[(wb + u5) * 64 + lane];
            unsigned long long g6 = gate[(wb + u6) * 64 + lane];
            unsigned long long g7 = gate[(wb + u7) * 64 + lane];
            #define PROC(tk, gk) \
                if (tk >= 0 && ((alive >> tk) & 1ull)) { \
                    if (lane == 0 && nf < FIRE_CAP) fire_ord[nf] = (w << 6) + tk; \
                    ++nf; sup |= gk; \
                    alive &= ~(1ull << tk); \
                    alive &= ~rdl64(gk, w); \
                }
            PROC(t0, g0) PROC(t1, g1) PROC(t2, g2) PROC(t3, g3)
            PROC(t4, g4) PROC(t5, g5) PROC(t6, g6) PROC(t7, g7)
            #undef PROC
        }
    }
    if (lane == 0) fire_cnt[0] = nf < FIRE_CAP ? nf : FIRE_CAP;
}

// ---------------- finalize: recompute suppression vs fires, write output ----------------
__global__ __launch_bounds__(256) void finalize(const float* __restrict__ sboxes,
                                                const float* __restrict__ sareas,
                                                const float* __restrict__ scores,
                                                const int* __restrict__ order,
                                                const float4* __restrict__ cboxes,
                                                const float* __restrict__ carea,
                                                const int* __restrict__ cidx,
                                                const int* __restrict__ fire_ord,
                                                const int* __restrict__ fire_cnt,
                                                float* __restrict__ out) {
    __shared__ float4 FB[FIRE_CAP];
    __shared__ float FA[FIRE_CAP];
    __shared__ int FP[FIRE_CAP];
    int tid = threadIdx.x;
    int fc = fire_cnt[0];
    for (int k = tid; k < fc; k += 256) {
        int o = fire_ord[k];
        FB[k] = cboxes[o];
        FA[k] = carea[o];
        FP[k] = cidx[o];   // sorted position of the fire
    }
    __syncthreads();
    int j = blockIdx.x * 256 + tid;   // sorted index
    float4 b = ((const float4*)sboxes)[j];
    float aj = sareas[j];
    bool supp = false;
    for (int k = 0; k < fc; ++k) {
        float4 f = FB[k];
        float ix = fminf(b.z, f.z) - fmaxf(b.x, f.x);
        float iy = fminf(b.w, f.w) - fmaxf(b.y, f.y);
        float inter = fmaxf(ix, 0.f) * fmaxf(iy, 0.f);
        float denom = FA[k] + aj - inter;
        if (FP[k] < j && inter > 0.85f * denom) {
            if (inter / denom > IOU_THRF) supp = true;
        }
    }
    int n = order[j];
    float m = supp ? 0.f : 1.f;
    out[(size_t)n * 5 + 0] = b.x * m;
    out[(size_t)n * 5 + 1] = b.y * m;
    out[(size_t)n * 5 + 2] = b.z * m;
    out[(size_t)n * 5 + 3] = b.w * m;
    out[(size_t)n * 5 + 4] = scores[n] * m;
}

extern "C" void kernel_launch(void* const* d_in, const int* in_sizes, int n_in,
                              void* d_out, int out_size, void* d_ws, size_t ws_size,
                              hipStream_t stream) {
    const float* x      = (const float*)d_in[0];
    const float* anchors= (const float*)d_in[1];
    const float* dw_w   = (const float*)d_in[2];
    const float* pw_w   = (const float*)d_in[3];
    const float* bn1g   = (const float*)d_in[4];
    const float* bn1b   = (const float*)d_in[5];
    const float* bn1m   = (const float*)d_in[6];
    const float* bn1v   = (const float*)d_in[7];
    const float* anc_w  = (const float*)d_in[8];
    const float* ag     = (const float*)d_in[9];
    const float* ab     = (const float*)d_in[10];
    const float* am     = (const float*)d_in[11];
    const float* av     = (const float*)d_in[12];
    const float* obj_w  = (const float*)d_in[13];
    const float* og     = (const float*)d_in[14];
    const float* ob     = (const float*)d_in[15];
    const float* om     = (const float*)d_in[16];
    const float* ov     = (const float*)d_in[17];
    float* out = (float*)d_out;

    char* ws = (char*)d_ws;
    size_t off = 0;
    auto alloc = [&](size_t bytes) -> char* {
        char* p = ws + off;
        off = (off + bytes + 255) & ~(size_t)255;
        return p;
    };
    float* h0      = (float*)alloc(256 * 1024 * 4);
    float* h1      = (float*)alloc(256 * 1024 * 4);
    float* boxes   = (float*)alloc(NBOX * 4 * 4);
    float* scores  = (float*)alloc(NBOX * 4);
    unsigned* rank = (unsigned*)alloc(NBOX * 4);
    int* order     = (int*)alloc(NBOX * 4);
    float* sboxes  = (float*)alloc(NBOX * 4 * 4);
    float* sareas  = (float*)alloc(NBOX * 4);
    unsigned long long* rnz64 = (unsigned long long*)alloc(NWORDS * 8);
    int* cidx      = (int*)alloc(CAND_CAP * 4);
    float4* cboxes = (float4*)alloc(CAND_CAP * 16);
    float* carea   = (float*)alloc(CAND_CAP * 4);
    int* knum      = (int*)alloc(256);
    int* fire_ord  = (int*)alloc(FIRE_CAP * 4);
    int* fire_cnt  = (int*)alloc(256);
    unsigned long long* gate = (unsigned long long*)alloc((size_t)CAND_CAP * 64 * 8);

    hipMemsetAsync(rank, 0, NBOX * 4, stream);
    hipMemsetAsync(rnz64, 0, NWORDS * 8, stream);

    dw_conv<<<1024, 256, 0, stream>>>(x, dw_w, h0);
    pw_conv<<<dim3(4, 64), 256, 0, stream>>>(h0, pw_w, bn1g, bn1b, bn1m, bn1v, h1);
    heads<<<dim3(4, 45), 256, 0, stream>>>(h1, anc_w, ag, ab, am, av,
                                           obj_w, og, ob, om, ov, anchors, boxes, scores);
    rank_partial<<<dim3(36, 8), 256, 0, stream>>>(scores, rank);
    scatter_sorted<<<36, 256, 0, stream>>>(boxes, rank, order, sboxes, sareas);
    cand_detect<<<NTILES, 256, 0, stream>>>(sboxes, sareas, rnz64);
    compact_cand<<<1, 64, 0, stream>>>(rnz64, sboxes, sareas, cidx, cboxes, carea, knum);
    gate_build<<<CAND_CAP / 4, 256, 0, stream>>>(cboxes, carea, knum, gate);
    nms_scan2<<<1, 64, 0, stream>>>(gate, knum, fire_ord, fire_cnt);
    finalize<<<36, 256, 0, stream>>>(sboxes, sareas, scores, order,
                                     cboxes, carea, cidx, fire_ord, fire_cnt, out);
}